// Round 12
// baseline (199.937 us; speedup 1.0000x reference)
//
#include <hip/hip_runtime.h>
#include <hip/hip_fp16.h>

// SymmetricContraction: out[n,c,i] = cubic polynomial in x[n,c,:] with
// species/channel-dependent coefficients (968 monomials).
//   coef[s,c,t,0:4] = mult_t * sum_k u[t,k,i] w[s,k,c]   (stored FP16)
//   out[n,c,i]      = sum_t coef[idx_n,c,t,i] * x_a x_b x_j   (math FP32)
// Pipeline (2 dispatches):
//   coef_setup : coef table (~10.5 MB ws, fp16, layout [s][c][t][i] so a
//                (s,c) column is 8 KB CONTIGUOUS); + species bucketing
//                (ATB=64) in one spare block; CT=8
//   contract   : WAVE = (bucket, channel). lane = atom. coef[s,c,t] is
//                wave-UNIFORM -> scalar s_load stream (8 KB contiguous);
//                all 968 terms accumulate in registers; exclusive (n,c)
//                ownership -> direct store to out. No LDS, no barriers,
//                no partials, no reduce dispatch.
// ws requirement: ~10.5 MiB.
// R1: counted-vmcnt + sched_barrier at APT=4 -> scratch spill, 2.2x worse.
// R2: TILE=16 hurt; CT 16->8 helped (~7us).
// R3: XCD-pinning: FETCH 60->43 MB but dur 46->73 (L2 contention).
// R4: direct per-lane vector loads: VGPR=64 capped MLP at ~5 loads.
// R5 WIN: TLP 2x (ATB 16->8); 155->135.
// R6 WIN: fp16 coef; 135->127.8. CHAMPION until now.
// R7 FAILED: cross-XCD fp32 atomic epilogue serializes.
// R8 DIAG: more blocks beyond ~4.6/CU add nothing.
// R9 FAILED: CT=4 doubled setup w-reload. Contract: 44us, VALUBusy 20%.
// R10 NEUTRAL: counted-vmcnt == syncthreads.
// R11 FAILED: per-wave private tiles 4x'd L2 requests; 137.5.
// => Six schedule variants of "stream coef to atom-threads" all ~44us:
//    stall is the coef VECTOR-load stream itself (~1200cy exposed/tile).
// R12 (this): change the DECOMPOSITION — coef made wave-uniform (scalar
//    path), single-pass register accumulation, reduce eliminated.

#define DD     16
#define NATOM  512
#define NCH    128
#define NSPEC  10
#define NTP    1024  // padded term count (table size)
#define NT     968   // real terms (tail 56 are zero -> skipped in contract)
#define ATB    64    // atoms per bucket == lanes per wave
#define MAXB   18    // >= sum_s ceil(cnt_s/64)  (<= 10 + 512/64 = 18)
#define CT     8     // terms per coef_setup block (16 and 4 both worse)

#define WS_DESC  0
#define WS_ORDER 1024
#define WS_COEF  8192
// fp16 coef: [s][c (128)][t (1024)][i (4)] halves -> 8 B per (s,c,t)
#define COEF_BYTES (NSPEC * NCH * NTP * 4 * 2)  // 10,485,760

// ---------------- compile-time term table ----------------
// pack: a | b<<5 | j<<10 | kind<<15 | mult<<18
// slots in contract: 0..15 -> x[d], 16 -> 1.0f, 17 -> 0.0f
struct TermTable { unsigned v[NTP]; };
constexpr TermTable build_terms() {
  TermTable T{};
  int t = 0;
  for (int a = 0; a < DD; a++)
    for (int b = a; b < DD; b++)
      for (int j = b; j < DD; j++) {
        unsigned m = (a == b && b == j) ? 1u : ((a == b || b == j) ? 3u : 6u);
        T.v[t++] = (unsigned)(a | (b << 5) | (j << 10) | (3u << 15) | (m << 18));
      }
  for (int a = 0; a < DD; a++)
    for (int b = a; b < DD; b++) {
      unsigned m = (a == b) ? 1u : 2u;
      T.v[t++] = (unsigned)(a | (b << 5) | (16 << 10) | (2u << 15) | (m << 18));
    }
  for (int a = 0; a < DD; a++)
    T.v[t++] = (unsigned)(a | (16 << 5) | (16 << 10) | (1u << 15) | (1u << 18));
  while (t < NTP) T.v[t++] = (unsigned)(17 | (17 << 5) | (17 << 10));
  return T;
}
constexpr TermTable TERMS = build_terms();

// ---------------- setup: species bucketing (ATB=64) ----------------
__device__ void do_setup(const int* __restrict__ index, int* __restrict__ desc,
                         int* __restrict__ order) {
  __shared__ int cnt[NSPEC], cursor[NSPEC], bbase[NSPEC + 1];
  const int tid = threadIdx.x;  // 0..127
  if (tid < NSPEC) { cnt[tid] = 0; cursor[tid] = 0; }
  __syncthreads();
  for (int i = tid; i < NATOM; i += 128) atomicAdd(&cnt[index[i]], 1);
  for (int i = tid; i < MAXB * ATB; i += 128) order[i] = -1;
  __syncthreads();
  if (tid == 0) {
    int base = 0;
    for (int s = 0; s < NSPEC; s++) { bbase[s] = base; base += (cnt[s] + ATB - 1) / ATB; }
    bbase[NSPEC] = base;
  }
  __syncthreads();
  for (int i = tid; i < NATOM; i += 128) {
    int s = index[i];
    int pos = atomicAdd(&cursor[s], 1);
    order[bbase[s] * ATB + pos] = i;
  }
  for (int i = tid; i < MAXB; i += 128) {
    int sp = -1;
    for (int s = 0; s < NSPEC; s++)
      if (i >= bbase[s] && i < bbase[s + 1]) sp = s;
    desc[i] = sp;
  }
}

// ---------------- coefficient build (+fused setup) ----------------
__global__ __launch_bounds__(128) void coef_setup_kernel(
    const float* __restrict__ u3_0, const float* __restrict__ w3_0,
    const float* __restrict__ u2_0, const float* __restrict__ w2_0,
    const float* __restrict__ u1_0, const float* __restrict__ w1_0,
    const float* __restrict__ u3_1, const float* __restrict__ w3_1,
    const float* __restrict__ u2_1, const float* __restrict__ w2_1,
    const float* __restrict__ u1_1, const float* __restrict__ w1_1,
    const int* __restrict__ index, int* __restrict__ desc,
    int* __restrict__ order, __half* __restrict__ coefh) {
  if (blockIdx.y == NTP / CT) {                // spare row: setup
    if (blockIdx.x == 0) do_setup(index, desc, order);
    return;
  }
  const int s = blockIdx.x;
  const int c = threadIdx.x;
  const int tbase = blockIdx.y * CT;

  __shared__ float us0[CT][23];
  __shared__ float us1[CT][99];

  // cooperative u staging (coalesced; addresses uniform per term, lane-split)
  for (int i = 0; i < CT; ++i) {
    const unsigned ev = TERMS.v[tbase + i];
    const int kind = (ev >> 15) & 7;
    const int a = ev & 31, b = (ev >> 5) & 31, j = (ev >> 10) & 31;
    if (kind == 3) {
      const int off = (a * DD + b) * DD + j;
      if (c < 23) us0[i][c] = u3_0[off * 23 + c];
      else if (c < 122) us1[i][c - 23] = u3_1[(size_t)off * 99 + (c - 23)];
    } else if (kind == 2) {
      const int off = a * DD + b;
      if (c < 4) us0[i][c] = u2_0[off * 4 + c];
      else if (c < 22) us1[i][c - 4] = u2_1[off * 18 + (c - 4)];
    } else if (kind == 1) {
      if (c < 1) us0[i][0] = u1_0[a];
      else if (c < 4) us1[i][c - 1] = u1_1[a * 3 + (c - 1)];
    }
  }
  __syncthreads();

  float r3_0[23], r3_1[33], r2_0[4], r2_1[6];
#pragma unroll
  for (int k = 0; k < 23; k++) r3_0[k] = w3_0[(s * 23 + k) * NCH + c];
#pragma unroll
  for (int k = 0; k < 33; k++) r3_1[k] = w3_1[(s * 33 + k) * NCH + c];
#pragma unroll
  for (int k = 0; k < 4; k++) r2_0[k] = w2_0[(s * 4 + k) * NCH + c];
#pragma unroll
  for (int k = 0; k < 6; k++) r2_1[k] = w2_1[(s * 6 + k) * NCH + c];
  const float r1_0 = w1_0[s * NCH + c];
  const float r1_1 = w1_1[s * NCH + c];

  // thread c's CT terms are CONTIGUOUS in the [s][c][t] layout: 64 B run
  uint2* outp = (uint2*)coefh + ((size_t)(s * NCH + c) * NTP + tbase);
  for (int i = 0; i < CT; ++i) {
    const unsigned ev = TERMS.v[tbase + i];
    const int kind = (ev >> 15) & 7;
    const float fm = (float)((ev >> 18) & 7);
    float s0 = 0.f, s1 = 0.f, s2 = 0.f, s3 = 0.f;
    if (kind == 3) {
#pragma unroll
      for (int k = 0; k < 23; k++) s0 += us0[i][k] * r3_0[k];
#pragma unroll
      for (int k = 0; k < 33; k++) {
        const float w = r3_1[k];
        s1 += us1[i][k * 3 + 0] * w;
        s2 += us1[i][k * 3 + 1] * w;
        s3 += us1[i][k * 3 + 2] * w;
      }
    } else if (kind == 2) {
#pragma unroll
      for (int k = 0; k < 4; k++) s0 += us0[i][k] * r2_0[k];
#pragma unroll
      for (int k = 0; k < 6; k++) {
        const float w = r2_1[k];
        s1 += us1[i][k * 3 + 0] * w;
        s2 += us1[i][k * 3 + 1] * w;
        s3 += us1[i][k * 3 + 2] * w;
      }
    } else if (kind == 1) {
      s0 = us0[i][0] * r1_0;
      s1 = us1[i][0] * r1_1;
      s2 = us1[i][1] * r1_1;
      s3 = us1[i][2] * r1_1;
    }
    union { __half2 h2[2]; uint2 u; } pk;
    pk.h2[0] = __floats2half2_rn(fm * s0, fm * s1);
    pk.h2[1] = __floats2half2_rn(fm * s2, fm * s3);
    outp[i] = pk.u;
  }
}

// ---------------- contract: wave-per-(bucket,channel), scalar coef ----------
__device__ __forceinline__ void load16(float (&xr)[18], const float* __restrict__ p) {
  const float4* q = (const float4*)p;
  const float4 v0 = q[0], v1 = q[1], v2 = q[2], v3 = q[3];
  xr[0] = v0.x; xr[1] = v0.y; xr[2] = v0.z; xr[3] = v0.w;
  xr[4] = v1.x; xr[5] = v1.y; xr[6] = v1.z; xr[7] = v1.w;
  xr[8] = v2.x; xr[9] = v2.y; xr[10] = v2.z; xr[11] = v2.w;
  xr[12] = v3.x; xr[13] = v3.y; xr[14] = v3.z; xr[15] = v3.w;
}

__global__ __launch_bounds__(64) void contract_kernel(const float* __restrict__ x,
                                                      const int* __restrict__ desc,
                                                      const int* __restrict__ order,
                                                      const __half* __restrict__ coefh,
                                                      float* __restrict__ out) {
  const int b = blockIdx.x;                    // atom bucket (<=64 atoms)
  const int c = blockIdx.y;                    // channel 0..127
  const int s = desc[b];
  if (s < 0) return;                           // uniform per block
  const int lane = threadIdx.x;                // == atom slot
  const int n = order[b * ATB + lane];

  float xr[18];
#pragma unroll
  for (int i = 0; i < DD; i++) xr[i] = 0.f;
  xr[16] = 1.f;
  xr[17] = 0.f;
  if (n >= 0) load16(xr, x + ((size_t)n * NCH + c) * DD);

  float ac[4] = {0.f, 0.f, 0.f, 0.f};

  // wave-uniform coef column: 8 KB contiguous -> scalar s_load stream
  const uint2* cc = (const uint2*)coefh + (size_t)(s * NCH + c) * NTP;

#pragma unroll
  for (int t = 0; t < NT; ++t) {
    const unsigned ev = TERMS.v[t];            // compile-time const
    const int ea = ev & 31, eb = (ev >> 5) & 31, ej = (ev >> 10) & 31;
    const uint2 raw = cc[t];                   // uniform addr -> s_load
    const float2 f01 = __half22float2(*reinterpret_cast<const __half2*>(&raw.x));
    const float2 f23 = __half22float2(*reinterpret_cast<const __half2*>(&raw.y));
    const float m = xr[ea] * xr[eb] * xr[ej];
    ac[0] += f01.x * m; ac[1] += f01.y * m;
    ac[2] += f23.x * m; ac[3] += f23.y * m;
  }

  if (n >= 0)
    *(float4*)(out + ((size_t)n * NCH + c) * 4) =
        float4{ac[0], ac[1], ac[2], ac[3]};
}

extern "C" void kernel_launch(void* const* d_in, const int* in_sizes, int n_in,
                              void* d_out, int out_size, void* d_ws, size_t ws_size,
                              hipStream_t stream) {
  const float* x    = (const float*)d_in[0];
  const int* index  = (const int*)d_in[1];
  const float* u3_0 = (const float*)d_in[2];
  const float* w3_0 = (const float*)d_in[3];
  const float* u2_0 = (const float*)d_in[4];
  const float* w2_0 = (const float*)d_in[5];
  const float* u1_0 = (const float*)d_in[6];
  const float* w1_0 = (const float*)d_in[7];
  const float* u3_1 = (const float*)d_in[8];
  const float* w3_1 = (const float*)d_in[9];
  const float* u2_1 = (const float*)d_in[10];
  const float* w2_1 = (const float*)d_in[11];
  const float* u1_1 = (const float*)d_in[12];
  const float* w1_1 = (const float*)d_in[13];
  float* out = (float*)d_out;

  char* ws = (char*)d_ws;
  int* desc      = (int*)(ws + WS_DESC);
  int* order     = (int*)(ws + WS_ORDER);
  __half* coefh  = (__half*)(ws + WS_COEF);

  coef_setup_kernel<<<dim3(NSPEC, NTP / CT + 1), 128, 0, stream>>>(
      u3_0, w3_0, u2_0, w2_0, u1_0, w1_0,
      u3_1, w3_1, u2_1, w2_1, u1_1, w1_1, index, desc, order, coefh);
  contract_kernel<<<dim3(MAXB, NCH), 64, 0, stream>>>(x, desc, order, coefh, out);
}

// Round 13
// 128.404 us; speedup vs baseline: 1.5571x; 1.5571x over previous
//
#include <hip/hip_runtime.h>
#include <hip/hip_fp16.h>

// SymmetricContraction: out[n,c,i] = cubic polynomial in x[n,c,:] with
// species/channel-dependent coefficients (968 monomials, padded to 1024).
//   coef[s,t,c,0:4] = mult_t * sum_k u[t,k,i] w[s,k,c]   (stored FP16)
//   out[n,c,i]      = sum_t coef[idx_n,t,c,i] * x_a x_b x_j   (math FP32)
// Pipeline (3 dispatches):  == R6 CHAMPION (127.8 us), restored verbatim ==
//   coef_setup : coef table (~10.5 MB ws, fp16, layout [s][half][t][c'][i]),
//                u staged in LDS cooperatively; + species-bucketed atom
//                order (one spare block); CT=8
//   contract   : m97-style LDS pipeline — fp16 coef tiles streamed via
//                global_load_lds (16B, async; 1 load/wave covers 2 terms),
//                double-buffered, __syncthreads per tile; fp32 accumulate.
//                TLP: APT=2 / ATB=8 -> ~1184 blocks (18.5 waves/CU)
//   reduce     : out = sum over 8 chunk partials (fp32)
// ws requirement: ~18.6 MiB.
// Session ledger:
// R1: counted-vmcnt + sched_barrier at APT=4 -> scratch spill, 2.2x worse.
// R2: TILE=16 hurt (46->57); CT 16->8 helped (~7us).
// R3: XCD-pinning cut FETCH 60->43 MB but dur 46->73 (L2 contention).
// R4: direct per-lane vector loads: VGPR=64 capped MLP at ~5 loads.
// R5 WIN: ATB 16->8 / APT 4->2 doubled TLP; total 155->135.
// R6 WIN: fp16 coef table halved the dominant stream; 135->127.8. CHAMPION.
// R7 FAILED (137): cross-XCD fp32 atomic epilogue serializes.
// R8 DIAG (129.8): TLP saturated at ATB=8.
// R9 FAILED (138.9): CT=4 doubled setup w-reload.
// R10 NEUTRAL (130.1): counted-vmcnt == syncthreads (no spill, no gain).
// R11 FAILED (137.5): per-wave private tiles 4x'd L2 request traffic.
// R12 FAILED (199.9): scalar-coef decomposition — s_load latency chain
//     (SGPR-capped prefetch) + 150 KB unrolled body I-cache cold start.
// => Seven schedule/decomposition variants of contract all >= the R6 form;
//    R6 restored as final.

#define DD     16
#define NATOM  512
#define NCH    128
#define NSPEC  10
#define NTP    1024  // 8 chunks x 128 terms
#define ATB    8     // atoms per eval block (same species)
#define APT    2     // atoms per thread
#define MAXB   74    // >= sum_s ceil(cnt_s/ATB) (worst case 72)
#define CHUNKS 8
#define NTC    128   // terms per chunk
#define TILE   8     // terms per LDS tile
#define NTILES (NTC / TILE)  // 16
#define CHALF  2     // channel halves (64 ch per block)
#define CT     8     // terms per coef block (16 and 4 both proven worse)

#define WS_DESC  0
#define WS_ORDER 1024
#define WS_COEF  8192
// fp16 coef: [s][half][t][c' (64)][i (4)] halves -> 8 B per (s,h,t,c')
#define COEF_BYTES (NSPEC * 2 * NTP * 64 * 4 * 2)  // 10,485,760
#define WS_PART  (WS_COEF + COEF_BYTES)            // partials: 8 x 1 MB

// ---------------- compile-time term table ----------------
// pack: a | b<<5 | j<<10 | kind<<15 | mult<<18
// slots in contract: 0..15 -> x[d], 16 -> 1.0f, 17 -> 0.0f
struct TermTable { unsigned v[NTP]; };
constexpr TermTable build_terms() {
  TermTable T{};
  int t = 0;
  for (int a = 0; a < DD; a++)
    for (int b = a; b < DD; b++)
      for (int j = b; j < DD; j++) {
        unsigned m = (a == b && b == j) ? 1u : ((a == b || b == j) ? 3u : 6u);
        T.v[t++] = (unsigned)(a | (b << 5) | (j << 10) | (3u << 15) | (m << 18));
      }
  for (int a = 0; a < DD; a++)
    for (int b = a; b < DD; b++) {
      unsigned m = (a == b) ? 1u : 2u;
      T.v[t++] = (unsigned)(a | (b << 5) | (16 << 10) | (2u << 15) | (m << 18));
    }
  for (int a = 0; a < DD; a++)
    T.v[t++] = (unsigned)(a | (16 << 5) | (16 << 10) | (1u << 15) | (1u << 18));
  while (t < NTP) T.v[t++] = (unsigned)(17 | (17 << 5) | (17 << 10));
  return T;
}
constexpr TermTable TERMS = build_terms();

// ---------------- setup: species bucketing ----------------
__device__ void do_setup(const int* __restrict__ index, int* __restrict__ desc,
                         int* __restrict__ order) {
  __shared__ int cnt[NSPEC], cursor[NSPEC], bbase[NSPEC + 1];
  const int tid = threadIdx.x;  // 0..127
  if (tid < NSPEC) { cnt[tid] = 0; cursor[tid] = 0; }
  __syncthreads();
  for (int i = tid; i < NATOM; i += 128) atomicAdd(&cnt[index[i]], 1);
  for (int i = tid; i < MAXB * ATB; i += 128) order[i] = -1;
  __syncthreads();
  if (tid == 0) {
    int base = 0;
    for (int s = 0; s < NSPEC; s++) { bbase[s] = base; base += (cnt[s] + ATB - 1) / ATB; }
    bbase[NSPEC] = base;
  }
  __syncthreads();
  for (int i = tid; i < NATOM; i += 128) {
    int s = index[i];
    int pos = atomicAdd(&cursor[s], 1);
    order[bbase[s] * ATB + pos] = i;
  }
  for (int i = tid; i < MAXB; i += 128) {
    int sp = -1;
    for (int s = 0; s < NSPEC; s++)
      if (i >= bbase[s] && i < bbase[s + 1]) sp = s;
    desc[i] = sp;
  }
}

// ---------------- coefficient build (+fused setup) ----------------
__global__ __launch_bounds__(128) void coef_setup_kernel(
    const float* __restrict__ u3_0, const float* __restrict__ w3_0,
    const float* __restrict__ u2_0, const float* __restrict__ w2_0,
    const float* __restrict__ u1_0, const float* __restrict__ w1_0,
    const float* __restrict__ u3_1, const float* __restrict__ w3_1,
    const float* __restrict__ u2_1, const float* __restrict__ w2_1,
    const float* __restrict__ u1_1, const float* __restrict__ w1_1,
    const int* __restrict__ index, int* __restrict__ desc,
    int* __restrict__ order, __half* __restrict__ coefh) {
  if (blockIdx.y == NTP / CT) {                // spare row: setup
    if (blockIdx.x == 0) do_setup(index, desc, order);
    return;
  }
  const int s = blockIdx.x;
  const int c = threadIdx.x;
  const int tbase = blockIdx.y * CT;

  __shared__ float us0[CT][23];
  __shared__ float us1[CT][99];

  // cooperative u staging (coalesced; addresses uniform per term, lane-split)
  for (int i = 0; i < CT; ++i) {
    const unsigned ev = TERMS.v[tbase + i];
    const int kind = (ev >> 15) & 7;
    const int a = ev & 31, b = (ev >> 5) & 31, j = (ev >> 10) & 31;
    if (kind == 3) {
      const int off = (a * DD + b) * DD + j;
      if (c < 23) us0[i][c] = u3_0[off * 23 + c];
      else if (c < 122) us1[i][c - 23] = u3_1[(size_t)off * 99 + (c - 23)];
    } else if (kind == 2) {
      const int off = a * DD + b;
      if (c < 4) us0[i][c] = u2_0[off * 4 + c];
      else if (c < 22) us1[i][c - 4] = u2_1[off * 18 + (c - 4)];
    } else if (kind == 1) {
      if (c < 1) us0[i][0] = u1_0[a];
      else if (c < 4) us1[i][c - 1] = u1_1[a * 3 + (c - 1)];
    }
  }
  __syncthreads();

  float r3_0[23], r3_1[33], r2_0[4], r2_1[6];
#pragma unroll
  for (int k = 0; k < 23; k++) r3_0[k] = w3_0[(s * 23 + k) * NCH + c];
#pragma unroll
  for (int k = 0; k < 33; k++) r3_1[k] = w3_1[(s * 33 + k) * NCH + c];
#pragma unroll
  for (int k = 0; k < 4; k++) r2_0[k] = w2_0[(s * 4 + k) * NCH + c];
#pragma unroll
  for (int k = 0; k < 6; k++) r2_1[k] = w2_1[(s * 6 + k) * NCH + c];
  const float r1_0 = w1_0[s * NCH + c];
  const float r1_1 = w1_1[s * NCH + c];

  for (int i = 0; i < CT; ++i) {
    const unsigned ev = TERMS.v[tbase + i];
    const int kind = (ev >> 15) & 7;
    const float fm = (float)((ev >> 18) & 7);
    float s0 = 0.f, s1 = 0.f, s2 = 0.f, s3 = 0.f;
    if (kind == 3) {
#pragma unroll
      for (int k = 0; k < 23; k++) s0 += us0[i][k] * r3_0[k];
#pragma unroll
      for (int k = 0; k < 33; k++) {
        const float w = r3_1[k];
        s1 += us1[i][k * 3 + 0] * w;
        s2 += us1[i][k * 3 + 1] * w;
        s3 += us1[i][k * 3 + 2] * w;
      }
    } else if (kind == 2) {
#pragma unroll
      for (int k = 0; k < 4; k++) s0 += us0[i][k] * r2_0[k];
#pragma unroll
      for (int k = 0; k < 6; k++) {
        const float w = r2_1[k];
        s1 += us1[i][k * 3 + 0] * w;
        s2 += us1[i][k * 3 + 1] * w;
        s3 += us1[i][k * 3 + 2] * w;
      }
    } else if (kind == 1) {
      s0 = us0[i][0] * r1_0;
      s1 = us1[i][0] * r1_1;
      s2 = us1[i][1] * r1_1;
      s3 = us1[i][2] * r1_1;
    }
    // pack 4 halves -> 8 B; layout [s][h][t][c'] with h=c>>6, c'=c&63
    union { __half2 h2[2]; uint2 u; } pk;
    pk.h2[0] = __floats2half2_rn(fm * s0, fm * s1);
    pk.h2[1] = __floats2half2_rn(fm * s2, fm * s3);
    const size_t off =
        (((size_t)(s * 2 + (c >> 6)) * NTP + (tbase + i)) * 64 + (c & 63));
    *(uint2*)((char*)coefh + off * 8) = pk.u;
  }
}

// ---------------- contract: LDS-pipelined polynomial eval ----------------
// One 16B/lane global_load_lds per wave covers 2 terms (1024 B contiguous):
// term-half row = 64 c' x 8 B = 512 B in the [s][h][t][c'] layout.
__device__ __forceinline__ void stage_tile(const unsigned* __restrict__ gbase,
                                           int t0_tile, float* dst_base,
                                           int wave, int lane) {
  const unsigned* g = gbase + (size_t)(t0_tile + 2 * wave) * 128 + lane * 4;
  __builtin_amdgcn_global_load_lds(
      (const __attribute__((address_space(1))) unsigned int*)g,
      (__attribute__((address_space(3))) unsigned int*)(dst_base + wave * 256),
      16, 0, 0);
}

template <int CH>
__device__ __forceinline__ void eval_chunk(const unsigned* __restrict__ gbase,
                                           float (*lbuf)[TILE * 128],
                                           int wave, int lane,
                                           const float (&xr)[APT][18],
                                           float (&ac)[APT][4]) {
  constexpr int T0 = CH * NTC;
  stage_tile(gbase, T0, &lbuf[0][0], wave, lane);
#pragma unroll
  for (int tile = 0; tile < NTILES; ++tile) {
    __syncthreads();  // drains vmcnt -> lbuf[tile&1] ready; prev compute done
    if (tile + 1 < NTILES)
      stage_tile(gbase, T0 + (tile + 1) * TILE, &lbuf[(tile + 1) & 1][0], wave, lane);
    const float* lb = &lbuf[tile & 1][0];
#pragma unroll
    for (int i = 0; i < TILE; ++i) {
      const unsigned ev = TERMS.v[T0 + tile * TILE + i];  // compile-time const
      const int ea = ev & 31, eb = (ev >> 5) & 31, ej = (ev >> 10) & 31;
      // 8 B/lane: 4 halves for this (term, c'); 2-way bank alias = free
      const uint2 raw = *(const uint2*)(lb + i * 128 + lane * 2);
      const float2 f01 = __half22float2(*reinterpret_cast<const __half2*>(&raw.x));
      const float2 f23 = __half22float2(*reinterpret_cast<const __half2*>(&raw.y));
#pragma unroll
      for (int k = 0; k < APT; ++k) {
        const float m = xr[k][ea] * xr[k][eb] * xr[k][ej];
        ac[k][0] += f01.x * m; ac[k][1] += f01.y * m;
        ac[k][2] += f23.x * m; ac[k][3] += f23.y * m;
      }
    }
  }
}

__device__ __forceinline__ void load16(float (&xr)[18], const float* __restrict__ p) {
  const float4* q = (const float4*)p;
  const float4 v0 = q[0], v1 = q[1], v2 = q[2], v3 = q[3];
  xr[0] = v0.x; xr[1] = v0.y; xr[2] = v0.z; xr[3] = v0.w;
  xr[4] = v1.x; xr[5] = v1.y; xr[6] = v1.z; xr[7] = v1.w;
  xr[8] = v2.x; xr[9] = v2.y; xr[10] = v2.z; xr[11] = v2.w;
  xr[12] = v3.x; xr[13] = v3.y; xr[14] = v3.z; xr[15] = v3.w;
}

__global__ __launch_bounds__(256, 4) void contract_kernel(const float* __restrict__ x,
                                                          const int* __restrict__ desc,
                                                          const int* __restrict__ order,
                                                          const __half* __restrict__ coefh,
                                                          float* __restrict__ partial) {
  const int s = desc[blockIdx.x];
  if (s < 0) return;                           // uniform per block
  const int lane = threadIdx.x & 63;
  const int wave = threadIdx.x >> 6;           // == atom group 0..3
  const int half = blockIdx.z;
  const int c = half * 64 + lane;

  __shared__ float lbuf[2][TILE * 128];        // 2 x 4 KB (fp16 coef)

  int n[APT];
#pragma unroll
  for (int k = 0; k < APT; k++) n[k] = order[blockIdx.x * ATB + wave * APT + k];

  float xr[APT][18];
#pragma unroll
  for (int k = 0; k < APT; k++) {
#pragma unroll
    for (int i = 0; i < DD; i++) xr[k][i] = 0.f;
    xr[k][16] = 1.f;
    xr[k][17] = 0.f;
  }
#pragma unroll
  for (int k = 0; k < APT; k++)
    if (n[k] >= 0) load16(xr[k], x + ((size_t)n[k] * NCH + c) * DD);

  float ac[APT][4];
#pragma unroll
  for (int k = 0; k < APT; k++) { ac[k][0] = 0.f; ac[k][1] = 0.f; ac[k][2] = 0.f; ac[k][3] = 0.f; }

  // [s][half] chunk base, dword units (term stride = 512 B = 128 dwords)
  const unsigned* gbase =
      (const unsigned*)coefh + (size_t)(s * 2 + half) * NTP * 128;

  switch (blockIdx.y) {
    case 0: eval_chunk<0>(gbase, lbuf, wave, lane, xr, ac); break;
    case 1: eval_chunk<1>(gbase, lbuf, wave, lane, xr, ac); break;
    case 2: eval_chunk<2>(gbase, lbuf, wave, lane, xr, ac); break;
    case 3: eval_chunk<3>(gbase, lbuf, wave, lane, xr, ac); break;
    case 4: eval_chunk<4>(gbase, lbuf, wave, lane, xr, ac); break;
    case 5: eval_chunk<5>(gbase, lbuf, wave, lane, xr, ac); break;
    case 6: eval_chunk<6>(gbase, lbuf, wave, lane, xr, ac); break;
    default: eval_chunk<7>(gbase, lbuf, wave, lane, xr, ac); break;
  }

  float* pb = partial + (size_t)blockIdx.y * (NATOM * NCH * 4);
#pragma unroll
  for (int k = 0; k < APT; k++)
    if (n[k] >= 0)
      *(float4*)(pb + ((size_t)n[k] * NCH + c) * 4) =
          float4{ac[k][0], ac[k][1], ac[k][2], ac[k][3]};
}

// ---------------- final reduction over chunks ----------------
__global__ __launch_bounds__(256) void reduce_kernel(const float4* __restrict__ partial,
                                                     float4* __restrict__ out) {
  const int i = blockIdx.x * 256 + threadIdx.x;  // 0 .. NATOM*NCH-1
  float4 s{0.f, 0.f, 0.f, 0.f};
#pragma unroll
  for (int ch = 0; ch < CHUNKS; ch++) {
    const float4 v = partial[(size_t)ch * (NATOM * NCH) + i];
    s.x += v.x; s.y += v.y; s.z += v.z; s.w += v.w;
  }
  out[i] = s;
}

extern "C" void kernel_launch(void* const* d_in, const int* in_sizes, int n_in,
                              void* d_out, int out_size, void* d_ws, size_t ws_size,
                              hipStream_t stream) {
  const float* x    = (const float*)d_in[0];
  const int* index  = (const int*)d_in[1];
  const float* u3_0 = (const float*)d_in[2];
  const float* w3_0 = (const float*)d_in[3];
  const float* u2_0 = (const float*)d_in[4];
  const float* w2_0 = (const float*)d_in[5];
  const float* u1_0 = (const float*)d_in[6];
  const float* w1_0 = (const float*)d_in[7];
  const float* u3_1 = (const float*)d_in[8];
  const float* w3_1 = (const float*)d_in[9];
  const float* u2_1 = (const float*)d_in[10];
  const float* w2_1 = (const float*)d_in[11];
  const float* u1_1 = (const float*)d_in[12];
  const float* w1_1 = (const float*)d_in[13];
  float* out = (float*)d_out;

  char* ws = (char*)d_ws;
  int* desc      = (int*)(ws + WS_DESC);
  int* order     = (int*)(ws + WS_ORDER);
  __half* coefh  = (__half*)(ws + WS_COEF);
  float* partial = (float*)(ws + WS_PART);

  coef_setup_kernel<<<dim3(NSPEC, NTP / CT + 1), 128, 0, stream>>>(
      u3_0, w3_0, u2_0, w2_0, u1_0, w1_0,
      u3_1, w3_1, u2_1, w2_1, u1_1, w1_1, index, desc, order, coefh);
  contract_kernel<<<dim3(MAXB, CHUNKS, CHALF), 256, 0, stream>>>(x, desc, order, coefh, partial);
  reduce_kernel<<<(NATOM * NCH) / 256, 256, 0, stream>>>((const float4*)partial, (float4*)out);
}